// Round 2
// baseline (1498.097 us; speedup 1.0000x reference)
//
#include <hip/hip_runtime.h>
#include <hip/hip_bf16.h>

// Problem constants: B=128, T=512, D=1024, H=128, 4H=512.
#define BATCH 128
#define TSTEPS 512
#define HID 128
#define GATES 512
#define M_TOTAL (BATCH * TSTEPS)  // 65536

typedef _Float16 h2_t  __attribute__((ext_vector_type(2)));
typedef _Float16 half4 __attribute__((ext_vector_type(4)));
typedef _Float16 half8 __attribute__((ext_vector_type(8)));
typedef float    f32x4 __attribute__((ext_vector_type(4)));

__device__ __forceinline__ float sigmoidf_fast(float x) {
    return 1.0f / (1.0f + __expf(-x));
}
__device__ __forceinline__ float tanhf_fast(float x) {
    return 1.0f - 2.0f / (__expf(2.0f * x) + 1.0f);
}
__device__ __forceinline__ float fdot2h(h2_t a, h2_t b, float c) {
#if __has_builtin(__builtin_amdgcn_fdot2)
    return __builtin_amdgcn_fdot2(a, b, c, false);
#else
    return c + (float)a[0] * (float)b[0] + (float)a[1] * (float)b[1];
#endif
}

// ---------------------------------------------------------------------------
// Preconvert W (512x1024 fp32) to f16 hi/lo split.
// ---------------------------------------------------------------------------
__global__ __launch_bounds__(256) void convert_w(
    const float* __restrict__ src, _Float16* __restrict__ hi, _Float16* __restrict__ lo)
{
    const int i = blockIdx.x * 256 + threadIdx.x;   // x4 elements, 131072 threads
    float4 v = ((const float4*)src)[i];
    half4 h, l;
    h[0] = (_Float16)v.x; l[0] = (_Float16)(v.x - (float)h[0]);
    h[1] = (_Float16)v.y; l[1] = (_Float16)(v.y - (float)h[1]);
    h[2] = (_Float16)v.z; l[2] = (_Float16)(v.z - (float)h[2]);
    h[3] = (_Float16)v.w; l[3] = (_Float16)(v.w - (float)h[3]);
    *(half4*)&hi[4 * i] = h;
    *(half4*)&lo[4 * i] = l;
}

// ---------------------------------------------------------------------------
// MFMA GEMM with fused f16 hi/lo split of A:
//   xg[m][n] = sum_k A[m][k]*W[n][k] + b0[n] + b1[n]
// via 3 products ah*wh + ah*wl + al*wh (dropped al*wl ~ 2^-22 relative).
// 128x128 tile, BK=32, 256 threads (4 waves, each a 4x4 grid of 16x16 tiles).
// ---------------------------------------------------------------------------
__global__ __launch_bounds__(256, 2) void gemm_mfma(
    const float* __restrict__ A,        // [M][1024] fp32
    const _Float16* __restrict__ Wh,    // [512][1024]
    const _Float16* __restrict__ Wl,
    const float* __restrict__ b0,
    const float* __restrict__ b1,
    float* __restrict__ xg)             // [M][512]
{
    constexpr int K = 1024;
    __shared__ __align__(16) _Float16 sXh[128 * 32];
    __shared__ __align__(16) _Float16 sXl[128 * 32];
    __shared__ __align__(16) _Float16 sWh[128 * 32];
    __shared__ __align__(16) _Float16 sWl[128 * 32];

    const int tid = threadIdx.x;
    const int lane = tid & 63, wv = tid >> 6;
    const int wm = wv & 1, wn = wv >> 1;
    const int n0 = blockIdx.x * 128;   // n fastest: adjacent blocks share A rows
    const int m0 = blockIdx.y * 128;

    const int ar = tid & 127, aks = (tid >> 7) * 16;
    const float* pA = A + (size_t)(m0 + ar) * K + aks;
    const _Float16* pWh0 = Wh + (size_t)(n0 + (tid & 127)) * K + (tid >> 7) * 8;
    const _Float16* pWl0 = Wl + (size_t)(n0 + (tid & 127)) * K + (tid >> 7) * 8;

    f32x4 acc[4][4];
    #pragma unroll
    for (int nt = 0; nt < 4; ++nt) {
        const int cn = n0 + wn * 64 + nt * 16 + (lane & 15);
        const float bv = b0[cn] + b1[cn];
        #pragma unroll
        for (int mt = 0; mt < 4; ++mt) acc[mt][nt] = (f32x4){bv, bv, bv, bv};
    }

    float xv[16];
    half8 w0h, w1h, w0l, w1l;
    #pragma unroll
    for (int j = 0; j < 4; ++j) *(float4*)&xv[4 * j] = *(const float4*)(pA + 4 * j);
    w0h = *(const half8*)(pWh0);      w1h = *(const half8*)(pWh0 + 16);
    w0l = *(const half8*)(pWl0);      w1l = *(const half8*)(pWl0 + 16);

    const int kb0 = (tid >> 7) * 2;
    for (int ks = 0; ks < 32; ++ks) {
        half8 hh0, hh1, hl0, hl1;
        #pragma unroll
        for (int j = 0; j < 8; ++j) {
            _Float16 h = (_Float16)xv[j];
            hh0[j] = h; hl0[j] = (_Float16)(xv[j] - (float)h);
        }
        #pragma unroll
        for (int j = 0; j < 8; ++j) {
            _Float16 h = (_Float16)xv[8 + j];
            hh1[j] = h; hl1[j] = (_Float16)(xv[8 + j] - (float)h);
        }
        if (ks) __syncthreads();    // previous compute done before LDS overwrite
        *(half8*)&sXh[(size_t)((kb0    ) * 128 + ar) * 8] = hh0;
        *(half8*)&sXh[(size_t)((kb0 + 1) * 128 + ar) * 8] = hh1;
        *(half8*)&sXl[(size_t)((kb0    ) * 128 + ar) * 8] = hl0;
        *(half8*)&sXl[(size_t)((kb0 + 1) * 128 + ar) * 8] = hl1;
        *(half8*)&sWh[(size_t)tid * 8]         = w0h;
        *(half8*)&sWh[(size_t)(tid + 256) * 8] = w1h;
        *(half8*)&sWl[(size_t)tid * 8]         = w0l;
        *(half8*)&sWl[(size_t)(tid + 256) * 8] = w1l;
        __syncthreads();

        if (ks < 31) {              // prefetch next K-step during MFMA
            const int kn = (ks + 1) * 32;
            #pragma unroll
            for (int j = 0; j < 4; ++j)
                *(float4*)&xv[4 * j] = *(const float4*)(pA + kn + 4 * j);
            w0h = *(const half8*)(pWh0 + kn);      w1h = *(const half8*)(pWh0 + kn + 16);
            w0l = *(const half8*)(pWl0 + kn);      w1l = *(const half8*)(pWl0 + kn + 16);
        }

        const int fr = lane & 15, kb = lane >> 4;
        half8 ah[4], al[4], bh[4], bl[4];
        #pragma unroll
        for (int mt = 0; mt < 4; ++mt) {
            const int idx = (kb * 128 + wm * 64 + mt * 16 + fr) * 8;
            ah[mt] = *(const half8*)&sXh[idx];
            al[mt] = *(const half8*)&sXl[idx];
        }
        #pragma unroll
        for (int nt = 0; nt < 4; ++nt) {
            const int idx = (kb * 128 + wn * 64 + nt * 16 + fr) * 8;
            bh[nt] = *(const half8*)&sWh[idx];
            bl[nt] = *(const half8*)&sWl[idx];
        }
        #pragma unroll
        for (int mt = 0; mt < 4; ++mt)
            #pragma unroll
            for (int nt = 0; nt < 4; ++nt) {
                acc[mt][nt] = __builtin_amdgcn_mfma_f32_16x16x32_f16(ah[mt], bh[nt], acc[mt][nt], 0, 0, 0);
                acc[mt][nt] = __builtin_amdgcn_mfma_f32_16x16x32_f16(ah[mt], bl[nt], acc[mt][nt], 0, 0, 0);
                acc[mt][nt] = __builtin_amdgcn_mfma_f32_16x16x32_f16(al[mt], bh[nt], acc[mt][nt], 0, 0, 0);
            }
    }

    // epilogue: C/D layout col=lane&15, row=(lane>>4)*4+r
    #pragma unroll
    for (int mt = 0; mt < 4; ++mt) {
        const int rm = m0 + wm * 64 + mt * 16 + (lane >> 4) * 4;
        #pragma unroll
        for (int nt = 0; nt < 4; ++nt) {
            const int cn = n0 + wn * 64 + nt * 16 + (lane & 15);
            #pragma unroll
            for (int r = 0; r < 4; ++r)
                xg[(size_t)(rm + r) * GATES + cn] = acc[mt][nt][r];
        }
    }
}

// ---------------------------------------------------------------------------
// Fused dual-layer recurrence. 256 blocks x 512 threads (8 waves).
// Blocks [0,128): layer-0 producer; [128,256): layer-1 consumer + FC head.
//
// v3 fix: __launch_bounds__(512, 1). With (512, 2) the allocator capped the
// kernel at ~128 VGPRs, which fits the PRODUCER path (64 weight h2-regs +
// working ~= 108, the measured VGPR_Count) but forces the CONSUMER's wi[]
// (64 more regs) to scratch. The consumer then re-reads ~256 B/thread/step
// of spilled weights from L2-cached scratch: 512thr x 256B = 128 KB/step/CU
// at ~56 B/cyc L2 ~= 2300 cyc/step, matching the measured 4200 cyc/step
// (invisible in FETCH_SIZE since scratch hits L2). Raising the cap to 256
// (2 waves/SIMD; grid is 1 block/CU anyway) keeps all weights in VGPRs.
//
// K-split (v2): thread (ks=tid>>7, gq=tid&127) computes PARTIAL dots over
// k in [32ks,32ks+32) for gates {gq+128q}. Partials via part[128][20] f32
// (80B stride, conflict-free b128). Combine threads (tid<128) sum, activate,
// update c/h. 2 barriers/step.
//
// Handoff batched x4: one flag release per 4 steps; consumer prefetches 4
// chunks >=5 steps ahead into an 8-deep LDS ring. Producer never waits.
// ---------------------------------------------------------------------------
__global__ __launch_bounds__(512, 1) void fused_rec2(
    const float* __restrict__ xg,     // [B*T][512], layer-0 biases folded
    const float* __restrict__ w_hh0,
    const float* __restrict__ w_ih1,
    const float* __restrict__ w_hh1,
    const float* __restrict__ b_ih1,
    const float* __restrict__ b_hh1,
    const float* __restrict__ fc_w,
    const float* __restrict__ fc_b,
    unsigned int* __restrict__ h1g,   // [128][512][64] h as half2-in-uint
    int* __restrict__ flags,          // [128][64], poisoned negative
    float* __restrict__ logits)       // [128][8]
{
    const int blk = blockIdx.x;
    const bool L1 = blk >= BATCH;
    const int b = blk & (BATCH - 1);
    const int tid = threadIdx.x;      // == gate index 128*ks + gq
    const int ks = tid >> 7;          // K-slice: k in [32ks, 32ks+32)
    const int gq = tid & 127;         // gate quadruple base

    __shared__ __align__(16) _Float16 h16[HID];        // h_{t-1} (this layer)
    __shared__ __align__(16) float part[128 * 20];     // [gq][ks*4+q], 80B stride
    __shared__ __align__(16) unsigned int hin[8][64];  // consumer h0 ring
    __shared__ __align__(16) float hfin[HID];

    // wh[q][4*jj+e]: h2 of w[(gq+128q)][32ks+8jj+2e .. +1]
    h2_t wh[4][16], wi[4][16];
    {
        const float* wsrc = (L1 ? w_hh1 : w_hh0);
        #pragma unroll
        for (int q = 0; q < 4; ++q) {
            const float4* w4 = (const float4*)(wsrc + (size_t)(gq + 128 * q) * HID + 32 * ks);
            #pragma unroll
            for (int i = 0; i < 8; ++i) {
                float4 v = w4[i];
                wh[q][2 * i]     = (h2_t){(_Float16)v.x, (_Float16)v.y};
                wh[q][2 * i + 1] = (h2_t){(_Float16)v.z, (_Float16)v.w};
            }
        }
    }
    float bias = 0.f;
    if (L1) {
        #pragma unroll
        for (int q = 0; q < 4; ++q) {
            const float4* w4 = (const float4*)(w_ih1 + (size_t)(gq + 128 * q) * HID + 32 * ks);
            #pragma unroll
            for (int i = 0; i < 8; ++i) {
                float4 v = w4[i];
                wi[q][2 * i]     = (h2_t){(_Float16)v.x, (_Float16)v.y};
                wi[q][2 * i + 1] = (h2_t){(_Float16)v.z, (_Float16)v.w};
            }
        }
        bias = b_ih1[tid] + b_hh1[tid];   // this thread folds bias of gate `tid` (q==ks)
    }

    if (tid < HID) h16[tid] = (_Float16)0.f;
    float c = 0.f;

    unsigned int* h1row = h1g + (size_t)b * TSTEPS * 64;
    int* flagb = flags + b * 64;

    if (L1 && tid < 64) {   // prologue: chunks 0..7 (flag>=8 covers all)
        while (__hip_atomic_load(&flagb[tid], __ATOMIC_ACQUIRE, __HIP_MEMORY_SCOPE_AGENT) < 8) {}
        #pragma unroll
        for (int d = 0; d < 8; ++d)
            hin[d][tid] = __hip_atomic_load(&h1row[(size_t)d * 64 + tid],
                                            __ATOMIC_RELAXED, __HIP_MEMORY_SCOPE_AGENT);
    }

    const float* xgb = xg + (size_t)b * TSTEPS * GATES + tid;   // gate `tid` (q==ks)
    float xcur[4], xnxt[4];
    if (!L1) {
        #pragma unroll
        for (int u = 0; u < 4; ++u) xcur[u] = xgb[(size_t)u * GATES];
    }
    __syncthreads();

    for (int t4 = 0; t4 < 128; ++t4) {
        if (!L1) {   // group-prefetch xg for next 4 steps (coalesced)
            const int tn = (t4 + 1 < 128) ? (t4 + 1) * 4 : t4 * 4;
            #pragma unroll
            for (int u = 0; u < 4; ++u) xnxt[u] = xgb[(size_t)(tn + u) * GATES];
        }
        #pragma unroll
        for (int u = 0; u < 4; ++u) {
            const int t = t4 * 4 + u;
            // ---- partial-dot phase: all 512 threads, K-slice [32ks,32ks+32)
            float p0 = 0.f, p1 = 0.f, p2 = 0.f, p3 = 0.f;
            {
                const half8* hv8 = ((const half8*)h16) + 4 * ks;  // 4 x b128 broadcast
                #pragma unroll
                for (int jj = 0; jj < 4; ++jj) {
                    half8 hh = hv8[jj];
                    #pragma unroll
                    for (int e = 0; e < 4; ++e) {
                        h2_t hp = (h2_t){hh[2 * e], hh[2 * e + 1]};
                        p0 = fdot2h(wh[0][4 * jj + e], hp, p0);
                        p1 = fdot2h(wh[1][4 * jj + e], hp, p1);
                        p2 = fdot2h(wh[2][4 * jj + e], hp, p2);
                        p3 = fdot2h(wh[3][4 * jj + e], hp, p3);
                    }
                }
            }
            if (L1) {
                float q0 = 0.f, q1 = 0.f, q2 = 0.f, q3 = 0.f;
                const half8* xv8 = ((const half8*)&hin[t & 7][0]) + 4 * ks;
                #pragma unroll
                for (int jj = 0; jj < 4; ++jj) {
                    half8 hh = xv8[jj];
                    #pragma unroll
                    for (int e = 0; e < 4; ++e) {
                        h2_t hp = (h2_t){hh[2 * e], hh[2 * e + 1]};
                        q0 = fdot2h(wi[0][4 * jj + e], hp, q0);
                        q1 = fdot2h(wi[1][4 * jj + e], hp, q1);
                        q2 = fdot2h(wi[2][4 * jj + e], hp, q2);
                        q3 = fdot2h(wi[3][4 * jj + e], hp, q3);
                    }
                }
                p0 += q0; p1 += q1; p2 += q2; p3 += q3;
            }
            {
                // fold this thread's own-gate scalar (gate tid == gq+128*ks -> slot q=ks)
                const float extra = L1 ? bias : xcur[u];
                if      (ks == 0) p0 += extra;
                else if (ks == 1) p1 += extra;
                else if (ks == 2) p2 += extra;
                else              p3 += extra;
            }
            *(f32x4*)&part[gq * 20 + ks * 4] = (f32x4){p0, p1, p2, p3};
            __syncthreads();
            // ---- combine + activations + state update: tid<128 (c-owners)
            if (tid < HID) {
                const f32x4* pr = (const f32x4*)&part[tid * 20];
                f32x4 v0 = pr[0], v1 = pr[1], v2 = pr[2], v3 = pr[3];
                const float si = (v0[0] + v1[0]) + (v2[0] + v3[0]);
                const float sf = (v0[1] + v1[1]) + (v2[1] + v3[1]);
                const float sg = (v0[2] + v1[2]) + (v2[2] + v3[2]);
                const float so = (v0[3] + v1[3]) + (v2[3] + v3[3]);
                const float ig = sigmoidf_fast(si);
                const float fg = sigmoidf_fast(sf);
                const float gg = tanhf_fast(sg);
                const float og = sigmoidf_fast(so);
                c = __fmaf_rn(fg, c, ig * gg);
                const float h = og * tanhf_fast(c);
                h16[tid] = (_Float16)h;
                if (L1 && t == TSTEPS - 1) hfin[tid] = h;
            }
            __syncthreads();
            if (!L1 && tid < 64) {
                __hip_atomic_store(&h1row[(size_t)t * 64 + tid], ((const unsigned int*)h16)[tid],
                                   __ATOMIC_RELAXED, __HIP_MEMORY_SCOPE_AGENT);
                if (u == 3)
                    __hip_atomic_store(&flagb[tid], t + 1,
                                       __ATOMIC_RELEASE, __HIP_MEMORY_SCOPE_AGENT);
            }
            if (L1 && tid < 64 && u == 3) {
                const int tgt = t + 5;            // chunks t+5..t+8
                if (tgt + 3 < TSTEPS) {
                    while (__hip_atomic_load(&flagb[tid], __ATOMIC_ACQUIRE,
                                             __HIP_MEMORY_SCOPE_AGENT) < tgt + 4) {}
                    #pragma unroll
                    for (int d = 0; d < 4; ++d)
                        hin[(tgt + d) & 7][tid] =
                            __hip_atomic_load(&h1row[(size_t)(tgt + d) * 64 + tid],
                                              __ATOMIC_RELAXED, __HIP_MEMORY_SCOPE_AGENT);
                }
            }
        }
        if (!L1) {
            xcur[0] = xnxt[0]; xcur[1] = xnxt[1]; xcur[2] = xnxt[2]; xcur[3] = xnxt[3];
        }
    }

    if (L1) {
        __syncthreads();
        if (tid < 8) {
            float s2 = fc_b[tid];
            const float* wr = fc_w + tid * HID;
            #pragma unroll 4
            for (int k2 = 0; k2 < HID; ++k2) s2 = __fmaf_rn(wr[k2], hfin[k2], s2);
            logits[b * 8 + tid] = s2;
        }
    }
}

// ---------------------------------------------------------------------------
extern "C" void kernel_launch(void* const* d_in, const int* in_sizes, int n_in,
                              void* d_out, int out_size, void* d_ws, size_t ws_size,
                              hipStream_t stream) {
    const float* x     = (const float*)d_in[0];
    const float* w_ih0 = (const float*)d_in[1];
    const float* w_hh0 = (const float*)d_in[2];
    const float* b_ih0 = (const float*)d_in[3];
    const float* b_hh0 = (const float*)d_in[4];
    const float* w_ih1 = (const float*)d_in[5];
    const float* w_hh1 = (const float*)d_in[6];
    const float* b_ih1 = (const float*)d_in[7];
    const float* b_hh1 = (const float*)d_in[8];
    const float* fc_w  = (const float*)d_in[9];
    const float* fc_b  = (const float*)d_in[10];
    float* out = (float*)d_out;

    // ws: xg 128MB | Wh 1MB | Wl 1MB | h1g 16MB | flags 32KB  (~146MB)
    char* ws = (char*)d_ws;
    float*        xgb   = (float*)ws;
    _Float16*     Whp   = (_Float16*)(ws + (size_t)M_TOTAL * GATES * 4);
    _Float16*     Wlp   = (_Float16*)(ws + (size_t)M_TOTAL * GATES * 4 + 1048576);
    unsigned int* h1g   = (unsigned int*)(ws + (size_t)M_TOTAL * GATES * 4 + 2097152);
    int*          flags = (int*)(ws + (size_t)M_TOTAL * GATES * 4 + 2097152
                                    + (size_t)BATCH * TSTEPS * 64 * 4);

    convert_w<<<dim3(512), dim3(256), 0, stream>>>(w_ih0, Whp, Wlp);
    gemm_mfma<<<dim3(4, 512), dim3(256), 0, stream>>>(x, Whp, Wlp, b_ih0, b_hh0, xgb);
    fused_rec2<<<dim3(2 * BATCH), dim3(512), 0, stream>>>(
        xgb, w_hh0, w_ih1, w_hh1, b_ih1, b_hh1, fc_w, fc_b, h1g, flags, out);
}

// Round 4
// 1444.449 us; speedup vs baseline: 1.0371x; 1.0371x over previous
//
#include <hip/hip_runtime.h>
#include <hip/hip_bf16.h>

// Problem constants: B=128, T=512, D=1024, H=128, 4H=512.
#define BATCH 128
#define TSTEPS 512
#define HID 128
#define GATES 512
#define M_TOTAL (BATCH * TSTEPS)  // 65536

typedef _Float16 h2_t  __attribute__((ext_vector_type(2)));
typedef _Float16 half4 __attribute__((ext_vector_type(4)));
typedef _Float16 half8 __attribute__((ext_vector_type(8)));
typedef float    f32x4 __attribute__((ext_vector_type(4)));

__device__ __forceinline__ float sigmoidf_fast(float x) {
    return 1.0f / (1.0f + __expf(-x));
}
__device__ __forceinline__ float tanhf_fast(float x) {
    return 1.0f - 2.0f / (__expf(2.0f * x) + 1.0f);
}
__device__ __forceinline__ float fdot2h(h2_t a, h2_t b, float c) {
#if __has_builtin(__builtin_amdgcn_fdot2)
    return __builtin_amdgcn_fdot2(a, b, c, false);
#else
    return c + (float)a[0] * (float)b[0] + (float)a[1] * (float)b[1];
#endif
}
// Register-pin: forces v to be materialized in a VGPR here and blocks the
// compiler from rematerializing (re-loading/re-converting) it later.
__device__ __forceinline__ void pin_h2(h2_t& v) {
    unsigned u = __builtin_bit_cast(unsigned, v);
    asm volatile("" : "+v"(u));
    v = __builtin_bit_cast(h2_t, u);
}

// ---------------------------------------------------------------------------
// Preconvert W (512x1024 fp32) to f16 hi/lo split.
// ---------------------------------------------------------------------------
__global__ __launch_bounds__(256) void convert_w(
    const float* __restrict__ src, _Float16* __restrict__ hi, _Float16* __restrict__ lo)
{
    const int i = blockIdx.x * 256 + threadIdx.x;   // x4 elements, 131072 threads
    float4 v = ((const float4*)src)[i];
    half4 h, l;
    h[0] = (_Float16)v.x; l[0] = (_Float16)(v.x - (float)h[0]);
    h[1] = (_Float16)v.y; l[1] = (_Float16)(v.y - (float)h[1]);
    h[2] = (_Float16)v.z; l[2] = (_Float16)(v.z - (float)h[2]);
    h[3] = (_Float16)v.w; l[3] = (_Float16)(v.w - (float)h[3]);
    *(half4*)&hi[4 * i] = h;
    *(half4*)&lo[4 * i] = l;
}

// ---------------------------------------------------------------------------
// MFMA GEMM with fused f16 hi/lo split of A:
//   xg[m][n] = sum_k A[m][k]*W[n][k] + b0[n] + b1[n]
// via 3 products ah*wh + ah*wl + al*wh (dropped al*wl ~ 2^-22 relative).
// 128x128 tile, BK=32, 256 threads (4 waves, each a 4x4 grid of 16x16 tiles).
// ---------------------------------------------------------------------------
__global__ __launch_bounds__(256, 2) void gemm_mfma(
    const float* __restrict__ A,        // [M][1024] fp32
    const _Float16* __restrict__ Wh,    // [512][1024]
    const _Float16* __restrict__ Wl,
    const float* __restrict__ b0,
    const float* __restrict__ b1,
    float* __restrict__ xg)             // [M][512]
{
    constexpr int K = 1024;
    __shared__ __align__(16) _Float16 sXh[128 * 32];
    __shared__ __align__(16) _Float16 sXl[128 * 32];
    __shared__ __align__(16) _Float16 sWh[128 * 32];
    __shared__ __align__(16) _Float16 sWl[128 * 32];

    const int tid = threadIdx.x;
    const int lane = tid & 63, wv = tid >> 6;
    const int wm = wv & 1, wn = wv >> 1;
    const int n0 = blockIdx.x * 128;   // n fastest: adjacent blocks share A rows
    const int m0 = blockIdx.y * 128;

    const int ar = tid & 127, aks = (tid >> 7) * 16;
    const float* pA = A + (size_t)(m0 + ar) * K + aks;
    const _Float16* pWh0 = Wh + (size_t)(n0 + (tid & 127)) * K + (tid >> 7) * 8;
    const _Float16* pWl0 = Wl + (size_t)(n0 + (tid & 127)) * K + (tid >> 7) * 8;

    f32x4 acc[4][4];
    #pragma unroll
    for (int nt = 0; nt < 4; ++nt) {
        const int cn = n0 + wn * 64 + nt * 16 + (lane & 15);
        const float bv = b0[cn] + b1[cn];
        #pragma unroll
        for (int mt = 0; mt < 4; ++mt) acc[mt][nt] = (f32x4){bv, bv, bv, bv};
    }

    float xv[16];
    half8 w0h, w1h, w0l, w1l;
    #pragma unroll
    for (int j = 0; j < 4; ++j) *(float4*)&xv[4 * j] = *(const float4*)(pA + 4 * j);
    w0h = *(const half8*)(pWh0);      w1h = *(const half8*)(pWh0 + 16);
    w0l = *(const half8*)(pWl0);      w1l = *(const half8*)(pWl0 + 16);

    const int kb0 = (tid >> 7) * 2;
    for (int ks = 0; ks < 32; ++ks) {
        half8 hh0, hh1, hl0, hl1;
        #pragma unroll
        for (int j = 0; j < 8; ++j) {
            _Float16 h = (_Float16)xv[j];
            hh0[j] = h; hl0[j] = (_Float16)(xv[j] - (float)h);
        }
        #pragma unroll
        for (int j = 0; j < 8; ++j) {
            _Float16 h = (_Float16)xv[8 + j];
            hh1[j] = h; hl1[j] = (_Float16)(xv[8 + j] - (float)h);
        }
        if (ks) __syncthreads();    // previous compute done before LDS overwrite
        *(half8*)&sXh[(size_t)((kb0    ) * 128 + ar) * 8] = hh0;
        *(half8*)&sXh[(size_t)((kb0 + 1) * 128 + ar) * 8] = hh1;
        *(half8*)&sXl[(size_t)((kb0    ) * 128 + ar) * 8] = hl0;
        *(half8*)&sXl[(size_t)((kb0 + 1) * 128 + ar) * 8] = hl1;
        *(half8*)&sWh[(size_t)tid * 8]         = w0h;
        *(half8*)&sWh[(size_t)(tid + 256) * 8] = w1h;
        *(half8*)&sWl[(size_t)tid * 8]         = w0l;
        *(half8*)&sWl[(size_t)(tid + 256) * 8] = w1l;
        __syncthreads();

        if (ks < 31) {              // prefetch next K-step during MFMA
            const int kn = (ks + 1) * 32;
            #pragma unroll
            for (int j = 0; j < 4; ++j)
                *(float4*)&xv[4 * j] = *(const float4*)(pA + kn + 4 * j);
            w0h = *(const half8*)(pWh0 + kn);      w1h = *(const half8*)(pWh0 + kn + 16);
            w0l = *(const half8*)(pWl0 + kn);      w1l = *(const half8*)(pWl0 + kn + 16);
        }

        const int fr = lane & 15, kb = lane >> 4;
        half8 ah[4], al[4], bh[4], bl[4];
        #pragma unroll
        for (int mt = 0; mt < 4; ++mt) {
            const int idx = (kb * 128 + wm * 64 + mt * 16 + fr) * 8;
            ah[mt] = *(const half8*)&sXh[idx];
            al[mt] = *(const half8*)&sXl[idx];
        }
        #pragma unroll
        for (int nt = 0; nt < 4; ++nt) {
            const int idx = (kb * 128 + wn * 64 + nt * 16 + fr) * 8;
            bh[nt] = *(const half8*)&sWh[idx];
            bl[nt] = *(const half8*)&sWl[idx];
        }
        #pragma unroll
        for (int mt = 0; mt < 4; ++mt)
            #pragma unroll
            for (int nt = 0; nt < 4; ++nt) {
                acc[mt][nt] = __builtin_amdgcn_mfma_f32_16x16x32_f16(ah[mt], bh[nt], acc[mt][nt], 0, 0, 0);
                acc[mt][nt] = __builtin_amdgcn_mfma_f32_16x16x32_f16(ah[mt], bl[nt], acc[mt][nt], 0, 0, 0);
                acc[mt][nt] = __builtin_amdgcn_mfma_f32_16x16x32_f16(al[mt], bh[nt], acc[mt][nt], 0, 0, 0);
            }
    }

    // epilogue: C/D layout col=lane&15, row=(lane>>4)*4+r
    #pragma unroll
    for (int mt = 0; mt < 4; ++mt) {
        const int rm = m0 + wm * 64 + mt * 16 + (lane >> 4) * 4;
        #pragma unroll
        for (int nt = 0; nt < 4; ++nt) {
            const int cn = n0 + wn * 64 + nt * 16 + (lane & 15);
            #pragma unroll
            for (int r = 0; r < 4; ++r)
                xg[(size_t)(rm + r) * GATES + cn] = acc[mt][nt][r];
        }
    }
}

// ---------------------------------------------------------------------------
// Fused dual-layer recurrence. 256 blocks x 1024 threads (16 waves).
// Blocks [0,128): layer-0 producer; [128,256): layer-1 consumer + FC head.
//
// v5: 8-way K-split so the CONSUMER register set fits by construction.
// Evidence trail: VGPR_Count=108 == 64 wh regs + working, i.e. no room for
// wi[4][16]; the compiler sank the wi load+convert into the t-loop
// (remat from read-only global), costing 512B/thread/step from L2
// (~4570 cyc/step ~= measured 4200). launch_bounds couldn't forbid remat.
// With 1024 threads each thread owns 4 gates x 16 k: wh[4][8]+wi[4][8] =
// 64 weight VGPRs; whole consumer ~105 regs < the 128 cap that 16 waves
// impose -- nothing left to sink or spill. pin_h2 kept as insurance.
// Total dot work, LDS traffic, 2 barriers/step, and the producer->consumer
// flag protocol are unchanged. Gate index == tid for tid<512 (ks<4), so xg
// prefetch stays coalesced; ks>=4 threads own no gate scalar.
// Partials: part[128][36] f32 (144B stride; b128 accesses land 2 lanes/bank
// per quarter-wave -> conflict-free). Combine threads (tid<128) sum 8
// partials/gate, activate, update c/h.
// ---------------------------------------------------------------------------
__global__ __launch_bounds__(1024, 1) void fused_rec2(
    const float* __restrict__ xg,     // [B*T][512], layer-0 biases folded
    const float* __restrict__ w_hh0,
    const float* __restrict__ w_ih1,
    const float* __restrict__ w_hh1,
    const float* __restrict__ b_ih1,
    const float* __restrict__ b_hh1,
    const float* __restrict__ fc_w,
    const float* __restrict__ fc_b,
    unsigned int* __restrict__ h1g,   // [128][512][64] h as half2-in-uint
    int* __restrict__ flags,          // [128][64], poisoned negative
    float* __restrict__ logits)       // [128][8]
{
    const int blk = blockIdx.x;
    const bool L1 = blk >= BATCH;
    const int b = blk & (BATCH - 1);
    const int tid = threadIdx.x;
    const int ks = tid >> 7;          // K-slice: k in [16ks, 16ks+16), ks in [0,8)
    const int gq = tid & 127;         // gate quadruple base
    const bool owns = (ks < 4);       // thread owns gate scalar for gate==tid (tid<512)

    __shared__ __align__(16) _Float16 h16[HID];        // h_{t-1} (this layer)
    __shared__ __align__(16) float part[128 * 36];     // [gq][ks*4+q], 144B stride
    __shared__ __align__(16) unsigned int hin[8][64];  // consumer h0 ring
    __shared__ __align__(16) float hfin[HID];

    // wh[q][4*jj+e]: h2 of w[(gq+128q)][16ks+8jj+2e .. +1]
    h2_t wh[4][8], wi[4][8];
    {
        const float* wsrc = (L1 ? w_hh1 : w_hh0);
        #pragma unroll
        for (int q = 0; q < 4; ++q) {
            const float4* w4 = (const float4*)(wsrc + (size_t)(gq + 128 * q) * HID + 16 * ks);
            #pragma unroll
            for (int i = 0; i < 4; ++i) {
                float4 v = w4[i];
                wh[q][2 * i]     = (h2_t){(_Float16)v.x, (_Float16)v.y};
                wh[q][2 * i + 1] = (h2_t){(_Float16)v.z, (_Float16)v.w};
            }
            #pragma unroll
            for (int i = 0; i < 8; ++i) pin_h2(wh[q][i]);
        }
    }
    float bias = 0.f;
    if (L1) {
        #pragma unroll
        for (int q = 0; q < 4; ++q) {
            const float4* w4 = (const float4*)(w_ih1 + (size_t)(gq + 128 * q) * HID + 16 * ks);
            #pragma unroll
            for (int i = 0; i < 4; ++i) {
                float4 v = w4[i];
                wi[q][2 * i]     = (h2_t){(_Float16)v.x, (_Float16)v.y};
                wi[q][2 * i + 1] = (h2_t){(_Float16)v.z, (_Float16)v.w};
            }
            #pragma unroll
            for (int i = 0; i < 8; ++i) pin_h2(wi[q][i]);
        }
        if (owns) bias = b_ih1[tid] + b_hh1[tid];   // gate == tid for ks<4
    }

    if (tid < HID) h16[tid] = (_Float16)0.f;
    float c = 0.f;

    unsigned int* h1row = h1g + (size_t)b * TSTEPS * 64;
    int* flagb = flags + b * 64;

    if (L1 && tid < 64) {   // prologue: chunks 0..7 (flag>=8 covers all)
        while (__hip_atomic_load(&flagb[tid], __ATOMIC_ACQUIRE, __HIP_MEMORY_SCOPE_AGENT) < 8) {}
        #pragma unroll
        for (int d = 0; d < 8; ++d)
            hin[d][tid] = __hip_atomic_load(&h1row[(size_t)d * 64 + tid],
                                            __ATOMIC_RELAXED, __HIP_MEMORY_SCOPE_AGENT);
    }

    const float* xgb = xg + (size_t)b * TSTEPS * GATES + tid;   // gate==tid (ks<4 only)
    float xcur[4], xnxt[4];
    if (!L1 && owns) {
        #pragma unroll
        for (int u = 0; u < 4; ++u) xcur[u] = xgb[(size_t)u * GATES];
    }
    __syncthreads();

    for (int t4 = 0; t4 < 128; ++t4) {
        if (!L1 && owns) {   // group-prefetch xg for next 4 steps (coalesced)
            const int tn = (t4 + 1 < 128) ? (t4 + 1) * 4 : t4 * 4;
            #pragma unroll
            for (int u = 0; u < 4; ++u) xnxt[u] = xgb[(size_t)(tn + u) * GATES];
        }
        #pragma unroll
        for (int u = 0; u < 4; ++u) {
            const int t = t4 * 4 + u;
            // ---- partial-dot phase: all 1024 threads, K-slice [16ks,16ks+16)
            float p0 = 0.f, p1 = 0.f, p2 = 0.f, p3 = 0.f;
            {
                const half8* hv8 = ((const half8*)h16) + 2 * ks;  // 2 x b128 broadcast
                #pragma unroll
                for (int jj = 0; jj < 2; ++jj) {
                    half8 hh = hv8[jj];
                    #pragma unroll
                    for (int e = 0; e < 4; ++e) {
                        h2_t hp = (h2_t){hh[2 * e], hh[2 * e + 1]};
                        p0 = fdot2h(wh[0][4 * jj + e], hp, p0);
                        p1 = fdot2h(wh[1][4 * jj + e], hp, p1);
                        p2 = fdot2h(wh[2][4 * jj + e], hp, p2);
                        p3 = fdot2h(wh[3][4 * jj + e], hp, p3);
                    }
                }
            }
            if (L1) {
                float q0 = 0.f, q1 = 0.f, q2 = 0.f, q3 = 0.f;
                const half8* xv8 = ((const half8*)&hin[t & 7][0]) + 2 * ks;
                #pragma unroll
                for (int jj = 0; jj < 2; ++jj) {
                    half8 hh = xv8[jj];
                    #pragma unroll
                    for (int e = 0; e < 4; ++e) {
                        h2_t hp = (h2_t){hh[2 * e], hh[2 * e + 1]};
                        q0 = fdot2h(wi[0][4 * jj + e], hp, q0);
                        q1 = fdot2h(wi[1][4 * jj + e], hp, q1);
                        q2 = fdot2h(wi[2][4 * jj + e], hp, q2);
                        q3 = fdot2h(wi[3][4 * jj + e], hp, q3);
                    }
                }
                p0 += q0; p1 += q1; p2 += q2; p3 += q3;
            }
            if (owns) {
                // fold this thread's own-gate scalar (gate tid -> slot q=ks)
                const float extra = L1 ? bias : xcur[u];
                if      (ks == 0) p0 += extra;
                else if (ks == 1) p1 += extra;
                else if (ks == 2) p2 += extra;
                else              p3 += extra;
            }
            *(f32x4*)&part[gq * 36 + ks * 4] = (f32x4){p0, p1, p2, p3};
            __syncthreads();
            // ---- combine + activations + state update: tid<128 (c-owners)
            if (tid < HID) {
                const f32x4* pr = (const f32x4*)&part[tid * 36];
                f32x4 s = pr[0];
                #pragma unroll
                for (int d = 1; d < 8; ++d) { f32x4 v = pr[d]; s[0]+=v[0]; s[1]+=v[1]; s[2]+=v[2]; s[3]+=v[3]; }
                const float ig = sigmoidf_fast(s[0]);
                const float fg = sigmoidf_fast(s[1]);
                const float gg = tanhf_fast(s[2]);
                const float og = sigmoidf_fast(s[3]);
                c = __fmaf_rn(fg, c, ig * gg);
                const float h = og * tanhf_fast(c);
                h16[tid] = (_Float16)h;
                if (L1 && t == TSTEPS - 1) hfin[tid] = h;
            }
            __syncthreads();
            if (!L1 && tid < 64) {
                __hip_atomic_store(&h1row[(size_t)t * 64 + tid], ((const unsigned int*)h16)[tid],
                                   __ATOMIC_RELAXED, __HIP_MEMORY_SCOPE_AGENT);
                if (u == 3)
                    __hip_atomic_store(&flagb[tid], t + 1,
                                       __ATOMIC_RELEASE, __HIP_MEMORY_SCOPE_AGENT);
            }
            if (L1 && tid < 64 && u == 3) {
                const int tgt = t + 5;            // chunks t+5..t+8
                if (tgt + 3 < TSTEPS) {
                    while (__hip_atomic_load(&flagb[tid], __ATOMIC_ACQUIRE,
                                             __HIP_MEMORY_SCOPE_AGENT) < tgt + 4) {}
                    #pragma unroll
                    for (int d = 0; d < 4; ++d)
                        hin[(tgt + d) & 7][tid] =
                            __hip_atomic_load(&h1row[(size_t)(tgt + d) * 64 + tid],
                                              __ATOMIC_RELAXED, __HIP_MEMORY_SCOPE_AGENT);
                }
            }
        }
        if (!L1 && owns) {
            xcur[0] = xnxt[0]; xcur[1] = xnxt[1]; xcur[2] = xnxt[2]; xcur[3] = xnxt[3];
        }
    }

    if (L1) {
        __syncthreads();
        if (tid < 8) {
            float s2 = fc_b[tid];
            const float* wr = fc_w + tid * HID;
            #pragma unroll 4
            for (int k2 = 0; k2 < HID; ++k2) s2 = __fmaf_rn(wr[k2], hfin[k2], s2);
            logits[b * 8 + tid] = s2;
        }
    }
}

// ---------------------------------------------------------------------------
extern "C" void kernel_launch(void* const* d_in, const int* in_sizes, int n_in,
                              void* d_out, int out_size, void* d_ws, size_t ws_size,
                              hipStream_t stream) {
    const float* x     = (const float*)d_in[0];
    const float* w_ih0 = (const float*)d_in[1];
    const float* w_hh0 = (const float*)d_in[2];
    const float* b_ih0 = (const float*)d_in[3];
    const float* b_hh0 = (const float*)d_in[4];
    const float* w_ih1 = (const float*)d_in[5];
    const float* w_hh1 = (const float*)d_in[6];
    const float* b_ih1 = (const float*)d_in[7];
    const float* b_hh1 = (const float*)d_in[8];
    const float* fc_w  = (const float*)d_in[9];
    const float* fc_b  = (const float*)d_in[10];
    float* out = (float*)d_out;

    // ws: xg 128MB | Wh 1MB | Wl 1MB | h1g 16MB | flags 32KB  (~146MB)
    char* ws = (char*)d_ws;
    float*        xgb   = (float*)ws;
    _Float16*     Whp   = (_Float16*)(ws + (size_t)M_TOTAL * GATES * 4);
    _Float16*     Wlp   = (_Float16*)(ws + (size_t)M_TOTAL * GATES * 4 + 1048576);
    unsigned int* h1g   = (unsigned int*)(ws + (size_t)M_TOTAL * GATES * 4 + 2097152);
    int*          flags = (int*)(ws + (size_t)M_TOTAL * GATES * 4 + 2097152
                                    + (size_t)BATCH * TSTEPS * 64 * 4);

    convert_w<<<dim3(512), dim3(256), 0, stream>>>(w_ih0, Whp, Wlp);
    gemm_mfma<<<dim3(4, 512), dim3(256), 0, stream>>>(x, Whp, Wlp, b_ih0, b_hh0, xgb);
    fused_rec2<<<dim3(2 * BATCH), dim3(1024), 0, stream>>>(
        xgb, w_hh0, w_ih1, w_hh1, b_ih1, b_hh1, fc_w, fc_b, h1g, flags, out);
}